// Round 15
// baseline (333.808 us; speedup 1.0000x reference)
//
#include <hip/hip_runtime.h>

#define Bb 2
#define Tt 4096
#define Dd 1024
#define Hh 16
#define QKd 64
#define VDd 64
#define BT (Bb*Tt)          // 8192
#define NCH 8
#define CHUNK (Tt/NCH)      // 512

// workspace layout (float units)
#define OFF_QF  0
#define OFF_KF  (OFF_QF + (size_t)BT*Dd)         // kfb: BT x 1024 ushort (bf16 featmap(k))
#define OFF_V   (OFF_KF + (size_t)BT*512)        // vfb: BT x 1024 ushort (bf16 v)
#define OFF_KVP (OFF_V + (size_t)BT*512)         // kv partials: NCH*32*4096 fp32
#define OFF_KSP (OFF_KVP + (size_t)NCH*32*4096)  // ksum partials: NCH*32*64
#define OFF_KV  (OFF_KSP + (size_t)NCH*32*64)    // 32*4096
#define OFF_KS  (OFF_KV + (size_t)32*4096)       // 32*64
#define OFF_XA  (OFF_KS + (size_t)32*64)         // xa: BT x 1024 ushort (bf16 of x)
#define OFF_WB  (OFF_XA + (size_t)BT*512)        // wb: 3072 x 1024 ushort (bf16 of WQ|WK|WV)
#define OFF_KVQB (OFF_WB + (size_t)3072*512)     // kvqb: 32 x 1024 x 64 ushort (bf16 of kvq)
#define OFF_QSB (OFF_KVQB + (size_t)32*1024*32)  // qsb: 32 x 4096 x 64 ushort (bf16 of z*q)

typedef __attribute__((ext_vector_type(8))) short short8;
typedef __attribute__((ext_vector_type(4))) float f32x4;

__device__ __forceinline__ float featmap(float x) {
    return x > 0.f ? x + 1.f : __expf(x);
}

__device__ __forceinline__ unsigned short bf16_rne(float f) {
    unsigned int u = __float_as_uint(f);
    unsigned int r = u + 0x7fffu + ((u >> 16) & 1u);
    return (unsigned short)(r >> 16);
}
__device__ __forceinline__ float bf16_to_f(unsigned short h) {
    return __uint_as_float(((unsigned int)h) << 16);
}

// merged cast: x[8192][1024] -> xa bf16 ; WQ|WK|WV -> wb[3072][1024] bf16
__global__ __launch_bounds__(256) void cast_all(const float* __restrict__ x,
                                                const float* __restrict__ WQ,
                                                const float* __restrict__ WK,
                                                const float* __restrict__ WV,
                                                unsigned short* __restrict__ xa,
                                                unsigned short* __restrict__ wbuf)
{
    int idx = blockIdx.x * 256 + threadIdx.x;   // < 2097152 + 786432
    if (idx < 2097152) {
        int m = idx >> 8;
        int c = (idx & 255) << 2;
        float4 v = *(const float4*)&x[(size_t)m * 1024 + c];
        ushort4 o;
        o.x = bf16_rne(v.x); o.y = bf16_rne(v.y); o.z = bf16_rne(v.z); o.w = bf16_rne(v.w);
        *(ushort4*)&xa[(size_t)m * 1024 + c] = o;
    } else {
        int r = idx - 2097152;
        int w = r >> 18;
        int rr = r & 262143;
        const float* src = (w == 0) ? WQ : ((w == 1) ? WK : WV);
        int m = rr >> 8;
        int c = (rr & 255) << 2;
        float4 v = *(const float4*)&src[(size_t)m * 1024 + c];
        ushort4 o;
        o.x = bf16_rne(v.x); o.y = bf16_rne(v.y); o.z = bf16_rne(v.z); o.w = bf16_rne(v.w);
        *(ushort4*)&wbuf[(size_t)(w*1024 + m) * 1024 + c] = o;
    }
}

#define GLLDS(gp, lp) __builtin_amdgcn_global_load_lds( \
    (const __attribute__((address_space(1))) void*)(gp), \
    (__attribute__((address_space(3))) void*)(lp), 16, 0, 0)

// Combined QKV projection, single-pass bf16: C[8192][3072] = xa x wb^T, K=1024.
// 256x256 tile, BK=64, 8 waves, counted-vmcnt(8) dbuf, XOR swizzle, setprio,
// XCD swizzle, 384 blocks, 128 KiB LDS. q -> fp32 (z path), k/v -> bf16.
__global__ __launch_bounds__(512, 2) void gemm_qkv(const unsigned short* __restrict__ A,
                                                   const unsigned short* __restrict__ W,
                                                   float* __restrict__ qf,
                                                   unsigned short* __restrict__ kfb,
                                                   unsigned short* __restrict__ vfb)
{
    extern __shared__ unsigned short lds[];
    const int tid  = threadIdx.x;
    const int lane = tid & 63;
    const int wave = tid >> 6;
    const int wm = (wave >> 2) * 128;   // 2 m-waves
    const int wn = (wave & 3) * 64;     // 4 n-waves
    // XCD-aware bijective swizzle: 384 blocks = 8 XCD x 48
    const int bid = blockIdx.x;
    const int nb = (bid & 7) * 48 + (bid >> 3);
    const int mblk = nb / 12, nblk = nb % 12;
    const int m0 = mblk * 256, n0 = nblk * 256;

    f32x4 acc[8][4] = {};

    auto stage = [&](int buf, int kt) {
        const int k0 = kt * 64;
        unsigned short* ab = &lds[buf * 32768];
        unsigned short* bb = ab + 16384;
        #pragma unroll
        for (int i = 0; i < 4; ++i) {
            int s = i * 512 + tid;          // 2048 slots x 16B = 32 KB (A tile)
            int row = s >> 3, g = s & 7;
            int gl = g ^ (row & 7);         // inverse-swizzled source (rule #21)
            GLLDS(&A[(size_t)(m0 + row) * 1024 + k0 + gl * 8], &ab[s * 8]);
        }
        #pragma unroll
        for (int i = 0; i < 4; ++i) {
            int s = i * 512 + tid;
            int row = s >> 3, g = s & 7;
            int gl = g ^ (row & 7);
            GLLDS(&W[(size_t)(n0 + row) * 1024 + k0 + gl * 8], &bb[s * 8]);
        }
    };

    stage(0, 0);
    for (int kt = 0; kt < 16; ++kt) {
        const int buf = kt & 1;
        if (kt + 1 < 16) {
            stage(buf ^ 1, kt + 1);
            asm volatile("s_waitcnt vmcnt(8)" ::: "memory");  // tile kt landed; kt+1 in flight
        } else {
            asm volatile("s_waitcnt vmcnt(0)" ::: "memory");
        }
        __builtin_amdgcn_s_barrier();
        __builtin_amdgcn_sched_barrier(0);
        const unsigned short* ab = &lds[buf * 32768];
        const unsigned short* bb = ab + 16384;
        #pragma unroll
        for (int ks = 0; ks < 2; ++ks) {
            short8 af[8], bf2[4];
            #pragma unroll
            for (int mi = 0; mi < 8; ++mi) {
                int row = wm + mi * 16 + (lane & 15);
                int g = ks * 4 + (lane >> 4);
                af[mi] = *(const short8*)&ab[row * 64 + (g ^ (row & 7)) * 8];
            }
            #pragma unroll
            for (int ni = 0; ni < 4; ++ni) {
                int row = wn + ni * 16 + (lane & 15);
                int g = ks * 4 + (lane >> 4);
                bf2[ni] = *(const short8*)&bb[row * 64 + (g ^ (row & 7)) * 8];
            }
            __builtin_amdgcn_s_setprio(1);
            #pragma unroll
            for (int mi = 0; mi < 8; ++mi)
                #pragma unroll
                for (int ni = 0; ni < 4; ++ni)
                    acc[mi][ni] = __builtin_amdgcn_mfma_f32_16x16x32_bf16(af[mi], bf2[ni], acc[mi][ni], 0, 0, 0);
            __builtin_amdgcn_s_setprio(0);
        }
        __builtin_amdgcn_s_barrier();
        __builtin_amdgcn_sched_barrier(0);
    }

    const int c0 = n0 & 1023;
    if (n0 < 1024) {
        #pragma unroll
        for (int mi = 0; mi < 8; ++mi)
            #pragma unroll
            for (int ni = 0; ni < 4; ++ni)
                #pragma unroll
                for (int r = 0; r < 4; ++r) {
                    int row = m0 + wm + mi*16 + ((lane >> 4) << 2) + r;
                    int col = c0 + wn + ni*16 + (lane & 15);
                    qf[(size_t)row * 1024 + col] = featmap(acc[mi][ni][r]);
                }
    } else if (n0 < 2048) {
        #pragma unroll
        for (int mi = 0; mi < 8; ++mi)
            #pragma unroll
            for (int ni = 0; ni < 4; ++ni)
                #pragma unroll
                for (int r = 0; r < 4; ++r) {
                    int row = m0 + wm + mi*16 + ((lane >> 4) << 2) + r;
                    int col = c0 + wn + ni*16 + (lane & 15);
                    kfb[(size_t)row * 1024 + col] = bf16_rne(featmap(acc[mi][ni][r]));
                }
    } else {
        #pragma unroll
        for (int mi = 0; mi < 8; ++mi)
            #pragma unroll
            for (int ni = 0; ni < 4; ++ni)
                #pragma unroll
                for (int r = 0; r < 4; ++r) {
                    int row = m0 + wm + mi*16 + ((lane >> 4) << 2) + r;
                    int col = c0 + wn + ni*16 + (lane & 15);
                    vfb[(size_t)row * 1024 + col] = bf16_rne(acc[mi][ni][r]);
                }
    }
}

// per (b,h), T-chunk: partial kv[64][64] and ksum[64]. bf16 in, fp32 accum.
__global__ __launch_bounds__(256) void kv_partial(const unsigned short* __restrict__ kfb,
        const unsigned short* __restrict__ vfb, float* __restrict__ kvpart,
        float* __restrict__ kspart)
{
    const int bh = blockIdx.x;
    const int ch = blockIdx.y;
    const int b = bh >> 4, h = bh & 15;
    __shared__ float sk[32][68];
    __shared__ float sv[32][68];
    const int tid = threadIdx.x;
    const int r0 = (tid >> 4) << 2;
    const int c0 = (tid & 15) << 2;
    const int which = tid >> 7;
    const int rr = (tid & 127) >> 2;
    const int d16 = (tid & 3) << 4;
    const unsigned short* src = which ? vfb : kfb;
    float acc[4][4] = {};
    float ksl = 0.f;
    for (int t0 = ch * CHUNK; t0 < (ch + 1) * CHUNK; t0 += 32) {
        const int t = t0 + rr;
        const unsigned short* sp = &src[(size_t)(b*Tt + t)*Dd + h*QKd + d16];
        ushort4 ua = *(const ushort4*)&sp[0];
        ushort4 ub = *(const ushort4*)&sp[4];
        ushort4 uc = *(const ushort4*)&sp[8];
        ushort4 ud = *(const ushort4*)&sp[12];
        float4 f0 = {bf16_to_f(ua.x), bf16_to_f(ua.y), bf16_to_f(ua.z), bf16_to_f(ua.w)};
        float4 f1 = {bf16_to_f(ub.x), bf16_to_f(ub.y), bf16_to_f(ub.z), bf16_to_f(ub.w)};
        float4 f2 = {bf16_to_f(uc.x), bf16_to_f(uc.y), bf16_to_f(uc.z), bf16_to_f(uc.w)};
        float4 f3 = {bf16_to_f(ud.x), bf16_to_f(ud.y), bf16_to_f(ud.z), bf16_to_f(ud.w)};
        __syncthreads();
        float* dst = which ? &sv[rr][d16] : &sk[rr][d16];
        *(float4*)&dst[0]  = f0;
        *(float4*)&dst[4]  = f1;
        *(float4*)&dst[8]  = f2;
        *(float4*)&dst[12] = f3;
        __syncthreads();
        #pragma unroll 8
        for (int s = 0; s < 32; ++s) {
            float4 k4v = *(const float4*)&sk[s][r0];
            float4 v4v = *(const float4*)&sv[s][c0];
            float kvv[4] = {k4v.x,k4v.y,k4v.z,k4v.w};
            float vvv[4] = {v4v.x,v4v.y,v4v.z,v4v.w};
            #pragma unroll
            for (int i = 0; i < 4; ++i)
                #pragma unroll
                for (int j = 0; j < 4; ++j)
                    acc[i][j] = fmaf(kvv[i], vvv[j], acc[i][j]);
        }
        if (tid < 64) {
            #pragma unroll 8
            for (int s = 0; s < 32; ++s) ksl += sk[s][tid];
        }
    }
    const size_t base = (size_t)(ch*32 + bh) * 4096;
    #pragma unroll
    for (int i = 0; i < 4; ++i) {
        float4 o = {acc[i][0], acc[i][1], acc[i][2], acc[i][3]};
        *(float4*)&kvpart[base + (r0+i)*64 + c0] = o;
    }
    if (tid < 64) kspart[(size_t)(ch*32 + bh)*64 + tid] = ksl;
}

__global__ __launch_bounds__(256) void kv_reduce(const float* __restrict__ kvpart,
        const float* __restrict__ kspart, float* __restrict__ kv, float* __restrict__ ksum)
{
    int g = blockIdx.x * 256 + threadIdx.x;
    if (g < 32*4096) {
        float s = 0.f;
        #pragma unroll
        for (int c = 0; c < NCH; ++c) s += kvpart[(size_t)c*(32*4096) + g];
        kv[g] = s;
    } else if (g < 32*4096 + 32*64) {
        int g2 = g - 32*4096;
        float s = 0.f;
        #pragma unroll
        for (int c = 0; c < NCH; ++c) s += kspart[(size_t)c*(32*64) + g2];
        ksum[g2] = s;
    }
}

// kvqb[bh][c][d] bf16 = kvq[d][c] = sum_m kv[bh][d][m]*Wproj[c][m]  (fp32 dot, bf16 store)
__global__ __launch_bounds__(256) void kvpb_kernel(const float* __restrict__ kv,
        const float* __restrict__ wproj, unsigned short* __restrict__ kvqb)
{
    int flat = blockIdx.x * 256 + threadIdx.x;
    int d = flat & 63;
    int c = (flat >> 6) & 1023;
    int bh = flat >> 16;
    const float4* kr = (const float4*)&kv[(size_t)(bh*64 + d)*64];
    const float4* wr = (const float4*)&wproj[(size_t)c*64];
    float s = 0.f;
    #pragma unroll
    for (int m = 0; m < 16; ++m) {
        float4 a = kr[m], bq = wr[m];
        s += a.x*bq.x + a.y*bq.y + a.z*bq.z + a.w*bq.w;
    }
    kvqb[((size_t)bh*1024 + c) * 64 + d] = bf16_rne(s);
}

// fused z + qsplit: z = 1/dot(q_row, ksum) in fp32 (correlated with numerator),
// then qsb[bh][t][d] = bf16(z * q). 16 lanes per (bt,h) row.
__global__ __launch_bounds__(256) void zq_kernel(const float* __restrict__ qf,
        const float* __restrict__ ksum, unsigned short* __restrict__ qsb)
{
    int row = blockIdx.x * 16 + (threadIdx.x >> 4);   // bt*16+h, 131072 rows
    int l16 = threadIdx.x & 15;
    int bt = row >> 4, h = row & 15;
    int b = bt >> 12, t = bt & 4095;
    float4 qv = *(const float4*)&qf[(size_t)bt*1024 + h*64 + l16*4];
    float4 kq = *(const float4*)&ksum[(size_t)(b*16 + h)*64 + l16*4];
    float p = qv.x*kq.x + qv.y*kq.y + qv.z*kq.z + qv.w*kq.w;
    p += __shfl_xor(p, 1); p += __shfl_xor(p, 2);
    p += __shfl_xor(p, 4); p += __shfl_xor(p, 8);
    float zv = 1.f / p;
    ushort4 o;
    o.x = bf16_rne(qv.x*zv); o.y = bf16_rne(qv.y*zv);
    o.z = bf16_rne(qv.z*zv); o.w = bf16_rne(qv.w*zv);
    *(ushort4*)&qsb[(((size_t)(b*16 + h)*4096 + t) << 6) + l16*4] = o;
}

// out = (z*q) @ kvq, single-pass bf16 MFMA, K=64.
// A-reuse c-loop. Grid (32 t-tiles, 32 bh) = 1024 blocks.
// A (qsb 128x64) staged ONCE as two LINEAR kt-planes (global_load_lds writes
// wave-uniform base + lane*16 — rule #21; R14's scattered dest was the bug).
// B double-buffered across 8 c-tiles, counted vmcnt(4). 48 KB LDS, 3 blocks/CU.
__global__ __launch_bounds__(256) void fgemm(const unsigned short* __restrict__ qsb,
        const unsigned short* __restrict__ kvqb, float* __restrict__ out)
{
    __shared__ unsigned short Als[2][128*32];      // [kt] plane, linear slots
    __shared__ unsigned short Bls[2][2][128*32];   // [buf][kt]
    const int tid  = threadIdx.x;
    const int lane = tid & 63;
    const int wave = tid >> 6;
    const int bh = blockIdx.y;
    const int b = bh >> 4, h = bh & 15;
    const int t0 = blockIdx.x * 128;
    const int wr = (wave >> 1) * 64;
    const int wc = (wave & 1) * 64;

    // stage A once: per kt-plane, 512 linear 16B slots (dest = base + slot*16)
    #pragma unroll
    for (int kt = 0; kt < 2; ++kt)
        #pragma unroll
        for (int i = 0; i < 2; ++i) {
            int s = i * 256 + tid;
            int row = s >> 2, g = s & 3;
            GLLDS(&qsb[((size_t)bh*4096 + t0 + row) * 64 + kt*32 + g * 8], &Als[kt][s * 8]);
        }
    auto stageB = [&](int buf, int c) {
        #pragma unroll
        for (int kt = 0; kt < 2; ++kt)
            #pragma unroll
            for (int i = 0; i < 2; ++i) {
                int s = i * 256 + tid;
                int row = s >> 2, g = s & 3;
                GLLDS(&kvqb[((size_t)bh*1024 + c*128 + row) * 64 + kt*32 + g * 8],
                      &Bls[buf][kt][s * 8]);
            }
    };
    stageB(0, 0);

    const int arow = (lane & 15) * 32 + (lane >> 4) * 8;
    for (int c = 0; c < 8; ++c) {
        const int buf = c & 1;
        if (c + 1 < 8) {
            stageB(buf ^ 1, c + 1);
            asm volatile("s_waitcnt vmcnt(4)" ::: "memory");  // A+cur B landed; next in flight
        } else {
            asm volatile("s_waitcnt vmcnt(0)" ::: "memory");
        }
        __builtin_amdgcn_s_barrier();
        __builtin_amdgcn_sched_barrier(0);

        f32x4 acc[4][4] = {};
        #pragma unroll
        for (int kt = 0; kt < 2; ++kt) {
            short8 af[4], bfr[4];
            #pragma unroll
            for (int m = 0; m < 4; ++m)
                af[m] = *(const short8*)&Als[kt][(wr + m*16)*32 + arow];
            #pragma unroll
            for (int n = 0; n < 4; ++n)
                bfr[n] = *(const short8*)&Bls[buf][kt][(wc + n*16)*32 + arow];
            #pragma unroll
            for (int m = 0; m < 4; ++m)
                #pragma unroll
                for (int n = 0; n < 4; ++n)
                    acc[m][n] = __builtin_amdgcn_mfma_f32_16x16x32_bf16(af[m], bfr[n], acc[m][n], 0, 0, 0);
        }

        #pragma unroll
        for (int m = 0; m < 4; ++m) {
            #pragma unroll
            for (int n = 0; n < 4; ++n) {
                #pragma unroll
                for (int r = 0; r < 4; ++r) {
                    int trow = t0 + wr + m*16 + ((lane >> 4) << 2) + r;
                    int col = c*128 + wc + n*16 + (lane & 15);
                    out[((size_t)(b*4096 + trow)*16 + h)*1024 + col] = acc[m][n][r];
                }
            }
        }
        __builtin_amdgcn_s_barrier();   // all reads of buf done before next overwrite
        __builtin_amdgcn_sched_barrier(0);
    }
}

extern "C" void kernel_launch(void* const* d_in, const int* in_sizes, int n_in,
                              void* d_out, int out_size, void* d_ws, size_t ws_size,
                              hipStream_t stream)
{
    const float* x  = (const float*)d_in[0];
    const float* WQ = (const float*)d_in[1];
    const float* WK = (const float*)d_in[2];
    const float* WV = (const float*)d_in[3];
    const float* Wp = (const float*)d_in[4];
    float* ws = (float*)d_ws;
    float* qf     = ws + OFF_QF;
    unsigned short* kfb = (unsigned short*)(ws + OFF_KF);
    unsigned short* vfb = (unsigned short*)(ws + OFF_V);
    float* kvpart = ws + OFF_KVP;
    float* kspart = ws + OFF_KSP;
    float* kv     = ws + OFF_KV;
    float* ksum   = ws + OFF_KS;
    unsigned short* xa   = (unsigned short*)(ws + OFF_XA);
    unsigned short* wb   = (unsigned short*)(ws + OFF_WB);
    unsigned short* kvqb = (unsigned short*)(ws + OFF_KVQB);
    unsigned short* qsb  = (unsigned short*)(ws + OFF_QSB);
    float* out = (float*)d_out;

    // allow 128 KiB dynamic LDS for gemm_qkv (idempotent; not a stream op)
    (void)hipFuncSetAttribute((const void*)gemm_qkv,
                              hipFuncAttributeMaxDynamicSharedMemorySize, 131072);

    dim3 blk(256);
    // merged bf16 casts (x + all three W) in one launch
    cast_all<<<(2097152 + 786432)/256, blk, 0, stream>>>(x, WQ, WK, WV, xa, wb);
    // combined QKV projection (single-pass bf16 MFMA, K=1024); q -> fp32, k/v -> bf16
    gemm_qkv<<<384, 512, 131072, stream>>>(xa, wb, qf, kfb, vfb);
    // kv & ksum reduction over T (bf16 in, fp32 accum)
    kv_partial<<<dim3(32, NCH), blk, 0, stream>>>(kfb, vfb, kvpart, kspart);
    kv_reduce<<<(32*4096 + 32*64 + 255)/256, blk, 0, stream>>>(kvpart, kspart, kv, ksum);
    // fold output projection into kv -> bf16
    kvpb_kernel<<<(32*1024*64)/256, blk, 0, stream>>>(kv, Wp, kvqb);
    // fused normalizer + z*q -> bf16 (fp32 q path, correlated rounding)
    zq_kernel<<<(BT*Hh)/16, blk, 0, stream>>>(qf, ksum, qsb);
    // final: out = (z*q) @ kvq, K=64, A-reuse c-loop
    fgemm<<<dim3(32, 32), blk, 0, stream>>>(qsb, kvqb, out);
}

// Round 16
// 315.021 us; speedup vs baseline: 1.0596x; 1.0596x over previous
//
#include <hip/hip_runtime.h>

#define Bb 2
#define Tt 4096
#define Dd 1024
#define Hh 16
#define QKd 64
#define VDd 64
#define BT (Bb*Tt)          // 8192
#define NCH 16
#define CHUNK (Tt/NCH)      // 256

// workspace layout (float units)
#define OFF_QF  0
#define OFF_KF  (OFF_QF + (size_t)BT*Dd)         // kfb: BT x 1024 ushort (bf16 featmap(k))
#define OFF_V   (OFF_KF + (size_t)BT*512)        // vfb: BT x 1024 ushort (bf16 v)
#define OFF_KVP (OFF_V + (size_t)BT*512)         // kv partials: NCH*32*4096 fp32
#define OFF_KSP (OFF_KVP + (size_t)NCH*32*4096)  // ksum partials: NCH*32*64
#define OFF_KV  (OFF_KSP + (size_t)NCH*32*64)    // 32*4096
#define OFF_KS  (OFF_KV + (size_t)32*4096)       // 32*64
#define OFF_XA  (OFF_KS + (size_t)32*64)         // xa: BT x 1024 ushort (bf16 of x)
#define OFF_WB  (OFF_XA + (size_t)BT*512)        // wb: 3072 x 1024 ushort (bf16 of WQ|WK|WV)
#define OFF_KVQB (OFF_WB + (size_t)3072*512)     // kvqb: 32 x 1024 x 64 ushort (bf16 of kvq)
#define OFF_QSB (OFF_KVQB + (size_t)32*1024*32)  // qsb: 32 x 4096 x 64 ushort (bf16 of z*q)

typedef __attribute__((ext_vector_type(8))) short short8;
typedef __attribute__((ext_vector_type(4))) float f32x4;

__device__ __forceinline__ float featmap(float x) {
    return x > 0.f ? x + 1.f : __expf(x);
}

__device__ __forceinline__ unsigned short bf16_rne(float f) {
    unsigned int u = __float_as_uint(f);
    unsigned int r = u + 0x7fffu + ((u >> 16) & 1u);
    return (unsigned short)(r >> 16);
}
__device__ __forceinline__ float bf16_to_f(unsigned short h) {
    return __uint_as_float(((unsigned int)h) << 16);
}

// cast x[8192][1024] f32 -> bf16
__global__ __launch_bounds__(256) void cast_a(const float* __restrict__ src,
                                              unsigned short* __restrict__ dst)
{
    int idx = blockIdx.x * 256 + threadIdx.x;
    int m = idx >> 8;
    int c = (idx & 255) << 2;
    float4 v = *(const float4*)&src[(size_t)m * 1024 + c];
    ushort4 o;
    o.x = bf16_rne(v.x); o.y = bf16_rne(v.y); o.z = bf16_rne(v.z); o.w = bf16_rne(v.w);
    *(ushort4*)&dst[(size_t)m * 1024 + c] = o;
}

// cast WQ|WK|WV (each [1024][1024] f32) -> wb[3072][1024] bf16
__global__ __launch_bounds__(256) void cast_w3(const float* __restrict__ WQ,
                                               const float* __restrict__ WK,
                                               const float* __restrict__ WV,
                                               unsigned short* __restrict__ dst)
{
    int idx = blockIdx.x * 256 + threadIdx.x;
    int w = idx >> 18;
    int r = idx & 262143;
    const float* src = (w == 0) ? WQ : ((w == 1) ? WK : WV);
    int m = r >> 8;
    int c = (r & 255) << 2;
    float4 v = *(const float4*)&src[(size_t)m * 1024 + c];
    ushort4 o;
    o.x = bf16_rne(v.x); o.y = bf16_rne(v.y); o.z = bf16_rne(v.z); o.w = bf16_rne(v.w);
    *(ushort4*)&dst[(size_t)(w*1024 + m) * 1024 + c] = o;
}

#define GLLDS(gp, lp) __builtin_amdgcn_global_load_lds( \
    (const __attribute__((address_space(1))) void*)(gp), \
    (__attribute__((address_space(3))) void*)(lp), 16, 0, 0)

// Combined QKV projection, single-pass bf16: C[8192][3072] = xa x wb^T, K=1024.
// 256x256 tile, BK=64, 8 waves, counted-vmcnt(8) dbuf, XOR swizzle, setprio,
// XCD swizzle, 384 blocks, 128 KiB LDS. q -> fp32 (z path), k/v -> bf16.
__global__ __launch_bounds__(512, 2) void gemm_qkv(const unsigned short* __restrict__ A,
                                                   const unsigned short* __restrict__ W,
                                                   float* __restrict__ qf,
                                                   unsigned short* __restrict__ kfb,
                                                   unsigned short* __restrict__ vfb)
{
    extern __shared__ unsigned short lds[];
    const int tid  = threadIdx.x;
    const int lane = tid & 63;
    const int wave = tid >> 6;
    const int wm = (wave >> 2) * 128;   // 2 m-waves
    const int wn = (wave & 3) * 64;     // 4 n-waves
    // XCD-aware bijective swizzle: 384 blocks = 8 XCD x 48
    const int bid = blockIdx.x;
    const int nb = (bid & 7) * 48 + (bid >> 3);
    const int mblk = nb / 12, nblk = nb % 12;
    const int m0 = mblk * 256, n0 = nblk * 256;

    f32x4 acc[8][4] = {};

    auto stage = [&](int buf, int kt) {
        const int k0 = kt * 64;
        unsigned short* ab = &lds[buf * 32768];
        unsigned short* bb = ab + 16384;
        #pragma unroll
        for (int i = 0; i < 4; ++i) {
            int s = i * 512 + tid;          // 2048 slots x 16B = 32 KB (A tile)
            int row = s >> 3, g = s & 7;
            int gl = g ^ (row & 7);         // inverse-swizzled source (rule #21)
            GLLDS(&A[(size_t)(m0 + row) * 1024 + k0 + gl * 8], &ab[s * 8]);
        }
        #pragma unroll
        for (int i = 0; i < 4; ++i) {
            int s = i * 512 + tid;
            int row = s >> 3, g = s & 7;
            int gl = g ^ (row & 7);
            GLLDS(&W[(size_t)(n0 + row) * 1024 + k0 + gl * 8], &bb[s * 8]);
        }
    };

    stage(0, 0);
    for (int kt = 0; kt < 16; ++kt) {
        const int buf = kt & 1;
        if (kt + 1 < 16) {
            stage(buf ^ 1, kt + 1);
            asm volatile("s_waitcnt vmcnt(8)" ::: "memory");  // tile kt landed; kt+1 in flight
        } else {
            asm volatile("s_waitcnt vmcnt(0)" ::: "memory");
        }
        __builtin_amdgcn_s_barrier();
        __builtin_amdgcn_sched_barrier(0);
        const unsigned short* ab = &lds[buf * 32768];
        const unsigned short* bb = ab + 16384;
        #pragma unroll
        for (int ks = 0; ks < 2; ++ks) {
            short8 af[8], bf2[4];
            #pragma unroll
            for (int mi = 0; mi < 8; ++mi) {
                int row = wm + mi * 16 + (lane & 15);
                int g = ks * 4 + (lane >> 4);
                af[mi] = *(const short8*)&ab[row * 64 + (g ^ (row & 7)) * 8];
            }
            #pragma unroll
            for (int ni = 0; ni < 4; ++ni) {
                int row = wn + ni * 16 + (lane & 15);
                int g = ks * 4 + (lane >> 4);
                bf2[ni] = *(const short8*)&bb[row * 64 + (g ^ (row & 7)) * 8];
            }
            __builtin_amdgcn_s_setprio(1);
            #pragma unroll
            for (int mi = 0; mi < 8; ++mi)
                #pragma unroll
                for (int ni = 0; ni < 4; ++ni)
                    acc[mi][ni] = __builtin_amdgcn_mfma_f32_16x16x32_bf16(af[mi], bf2[ni], acc[mi][ni], 0, 0, 0);
            __builtin_amdgcn_s_setprio(0);
        }
        __builtin_amdgcn_s_barrier();
        __builtin_amdgcn_sched_barrier(0);
    }

    const int c0 = n0 & 1023;
    if (n0 < 1024) {
        #pragma unroll
        for (int mi = 0; mi < 8; ++mi)
            #pragma unroll
            for (int ni = 0; ni < 4; ++ni)
                #pragma unroll
                for (int r = 0; r < 4; ++r) {
                    int row = m0 + wm + mi*16 + ((lane >> 4) << 2) + r;
                    int col = c0 + wn + ni*16 + (lane & 15);
                    qf[(size_t)row * 1024 + col] = featmap(acc[mi][ni][r]);
                }
    } else if (n0 < 2048) {
        #pragma unroll
        for (int mi = 0; mi < 8; ++mi)
            #pragma unroll
            for (int ni = 0; ni < 4; ++ni)
                #pragma unroll
                for (int r = 0; r < 4; ++r) {
                    int row = m0 + wm + mi*16 + ((lane >> 4) << 2) + r;
                    int col = c0 + wn + ni*16 + (lane & 15);
                    kfb[(size_t)row * 1024 + col] = bf16_rne(featmap(acc[mi][ni][r]));
                }
    } else {
        #pragma unroll
        for (int mi = 0; mi < 8; ++mi)
            #pragma unroll
            for (int ni = 0; ni < 4; ++ni)
                #pragma unroll
                for (int r = 0; r < 4; ++r) {
                    int row = m0 + wm + mi*16 + ((lane >> 4) << 2) + r;
                    int col = c0 + wn + ni*16 + (lane & 15);
                    vfb[(size_t)row * 1024 + col] = bf16_rne(acc[mi][ni][r]);
                }
    }
}

// per (b,h), T-chunk: partial kv[64][64] and ksum[64]  (bf16 inputs, fp32 accumulate)
__global__ __launch_bounds__(256) void kv_partial(const unsigned short* __restrict__ kfb,
        const unsigned short* __restrict__ vfb, float* __restrict__ kvpart,
        float* __restrict__ kspart)
{
    const int bh = blockIdx.x;
    const int ch = blockIdx.y;
    const int b = bh >> 4, h = bh & 15;
    __shared__ float sk[8][64];
    __shared__ float sv[8][64];
    const int tid = threadIdx.x;
    const int r0 = (tid >> 4) << 2;
    const int c0 = (tid & 15) << 2;
    const int tt = tid >> 5;
    const int rem = tid & 31;
    const int which = rem >> 4;
    const int d4 = (rem & 15) << 2;
    const unsigned short* src = which ? vfb : kfb;
    float acc[4][4] = {};
    float ksl = 0.f;
    for (int t0 = ch * CHUNK; t0 < (ch + 1) * CHUNK; t0 += 8) {
        const int t = t0 + tt;
        ushort4 val = *(const ushort4*)&src[(size_t)(b*Tt + t)*Dd + h*QKd + d4];
        float4 f;
        f.x = bf16_to_f(val.x); f.y = bf16_to_f(val.y);
        f.z = bf16_to_f(val.z); f.w = bf16_to_f(val.w);
        __syncthreads();
        if (which) *(float4*)&sv[tt][d4] = f;
        else       *(float4*)&sk[tt][d4] = f;
        __syncthreads();
        #pragma unroll
        for (int s = 0; s < 8; ++s) {
            float4 k4v = *(const float4*)&sk[s][r0];
            float4 v4v = *(const float4*)&sv[s][c0];
            float kvv[4] = {k4v.x,k4v.y,k4v.z,k4v.w};
            float vvv[4] = {v4v.x,v4v.y,v4v.z,v4v.w};
            #pragma unroll
            for (int i = 0; i < 4; ++i)
                #pragma unroll
                for (int j = 0; j < 4; ++j)
                    acc[i][j] = fmaf(kvv[i], vvv[j], acc[i][j]);
        }
        if (tid < 64) {
            #pragma unroll
            for (int s = 0; s < 8; ++s) ksl += sk[s][tid];
        }
    }
    const size_t base = (size_t)(ch*32 + bh) * 4096;
    #pragma unroll
    for (int i = 0; i < 4; ++i) {
        float4 o = {acc[i][0], acc[i][1], acc[i][2], acc[i][3]};
        *(float4*)&kvpart[base + (r0+i)*64 + c0] = o;
    }
    if (tid < 64) kspart[(size_t)(ch*32 + bh)*64 + tid] = ksl;
}

__global__ __launch_bounds__(256) void kv_reduce(const float* __restrict__ kvpart,
        const float* __restrict__ kspart, float* __restrict__ kv, float* __restrict__ ksum)
{
    int g = blockIdx.x * 256 + threadIdx.x;
    if (g < 32*4096) {
        float s = 0.f;
        #pragma unroll
        for (int c = 0; c < NCH; ++c) s += kvpart[(size_t)c*(32*4096) + g];
        kv[g] = s;
    } else if (g < 32*4096 + 32*64) {
        int g2 = g - 32*4096;
        float s = 0.f;
        #pragma unroll
        for (int c = 0; c < NCH; ++c) s += kspart[(size_t)c*(32*64) + g2];
        ksum[g2] = s;
    }
}

// kvqb[bh][c][d] bf16 = kvq[d][c] = sum_m kv[bh][d][m]*Wproj[c][m]  (fp32 dot, bf16 store)
__global__ __launch_bounds__(256) void kvpb_kernel(const float* __restrict__ kv,
        const float* __restrict__ wproj, unsigned short* __restrict__ kvqb)
{
    int flat = blockIdx.x * 256 + threadIdx.x;
    int d = flat & 63;
    int c = (flat >> 6) & 1023;
    int bh = flat >> 16;
    const float4* kr = (const float4*)&kv[(size_t)(bh*64 + d)*64];
    const float4* wr = (const float4*)&wproj[(size_t)c*64];
    float s = 0.f;
    #pragma unroll
    for (int m = 0; m < 16; ++m) {
        float4 a = kr[m], bq = wr[m];
        s += a.x*bq.x + a.y*bq.y + a.z*bq.z + a.w*bq.w;
    }
    kvqb[((size_t)bh*1024 + c) * 64 + d] = bf16_rne(s);
}

// fused z + qsplit: z = 1/dot(q_row, ksum) in fp32 (correlated with numerator),
// then qsb[bh][t][d] = bf16(z * q). 16 lanes per (bt,h) row.
__global__ __launch_bounds__(256) void zq_kernel(const float* __restrict__ qf,
        const float* __restrict__ ksum, unsigned short* __restrict__ qsb)
{
    int row = blockIdx.x * 16 + (threadIdx.x >> 4);   // bt*16+h, 131072 rows
    int l16 = threadIdx.x & 15;
    int bt = row >> 4, h = row & 15;
    int b = bt >> 12, t = bt & 4095;
    float4 qv = *(const float4*)&qf[(size_t)bt*1024 + h*64 + l16*4];
    float4 kq = *(const float4*)&ksum[(size_t)(b*16 + h)*64 + l16*4];
    float p = qv.x*kq.x + qv.y*kq.y + qv.z*kq.z + qv.w*kq.w;
    p += __shfl_xor(p, 1); p += __shfl_xor(p, 2);
    p += __shfl_xor(p, 4); p += __shfl_xor(p, 8);
    float zv = 1.f / p;
    ushort4 o;
    o.x = bf16_rne(qv.x*zv); o.y = bf16_rne(qv.y*zv);
    o.z = bf16_rne(qv.z*zv); o.w = bf16_rne(qv.w*zv);
    *(ushort4*)&qsb[(((size_t)(b*16 + h)*4096 + t) << 6) + l16*4] = o;
}

// out = (z*q) @ kvq, single-pass bf16 MFMA, K=64 as 2 K-steps of 32.
// 128x128 tile, 4 waves, global_load_lds dbuf (32 KB LDS, high occupancy).
__global__ __launch_bounds__(256) void fgemm(const unsigned short* __restrict__ qsb,
        const unsigned short* __restrict__ kvqb, float* __restrict__ out)
{
    __shared__ unsigned short Als[2][128*32];
    __shared__ unsigned short Bls[2][128*32];
    const int tid  = threadIdx.x;
    const int lane = tid & 63;
    const int wave = tid >> 6;
    const int bh = blockIdx.z;
    const int b = bh >> 4, h = bh & 15;
    const int t0 = blockIdx.y * 128;
    const int c0 = blockIdx.x * 128;
    const int wr = (wave >> 1) * 64;
    const int wc = (wave & 1) * 64;
    f32x4 acc[4][4] = {};

    auto stage = [&](int buf, int kt) {
        const int k0 = kt * 32;
        #pragma unroll
        for (int i = 0; i < 2; ++i) {
            int s = i * 256 + tid;
            int row = s >> 2, g = s & 3;
            GLLDS(&qsb[((size_t)bh*4096 + t0 + row) * 64 + k0 + g * 8], &Als[buf][s * 8]);
            GLLDS(&kvqb[((size_t)bh*1024 + c0 + row) * 64 + k0 + g * 8], &Bls[buf][s * 8]);
        }
    };

    stage(0, 0);
    const int arow = (lane & 15) * 32 + (lane >> 4) * 8;
    for (int kt = 0; kt < 2; ++kt) {
        const int buf = kt & 1;
        __syncthreads();
        if (kt + 1 < 2) stage(buf ^ 1, kt + 1);
        short8 af[4], bfr[4];
        #pragma unroll
        for (int m = 0; m < 4; ++m)
            af[m] = *(const short8*)&Als[buf][(wr + m*16)*32 + arow];
        #pragma unroll
        for (int n = 0; n < 4; ++n)
            bfr[n] = *(const short8*)&Bls[buf][(wc + n*16)*32 + arow];
        #pragma unroll
        for (int m = 0; m < 4; ++m)
            #pragma unroll
            for (int n = 0; n < 4; ++n)
                acc[m][n] = __builtin_amdgcn_mfma_f32_16x16x32_bf16(af[m], bfr[n], acc[m][n], 0, 0, 0);
    }

    #pragma unroll
    for (int m = 0; m < 4; ++m) {
        #pragma unroll
        for (int n = 0; n < 4; ++n) {
            #pragma unroll
            for (int r = 0; r < 4; ++r) {
                int trow = t0 + wr + m*16 + ((lane >> 4) << 2) + r;
                int col = c0 + wc + n*16 + (lane & 15);
                out[((size_t)(b*4096 + trow)*16 + h)*1024 + col] = acc[m][n][r];
            }
        }
    }
}

extern "C" void kernel_launch(void* const* d_in, const int* in_sizes, int n_in,
                              void* d_out, int out_size, void* d_ws, size_t ws_size,
                              hipStream_t stream)
{
    const float* x  = (const float*)d_in[0];
    const float* WQ = (const float*)d_in[1];
    const float* WK = (const float*)d_in[2];
    const float* WV = (const float*)d_in[3];
    const float* Wp = (const float*)d_in[4];
    float* ws = (float*)d_ws;
    float* qf     = ws + OFF_QF;
    unsigned short* kfb = (unsigned short*)(ws + OFF_KF);
    unsigned short* vfb = (unsigned short*)(ws + OFF_V);
    float* kvpart = ws + OFF_KVP;
    float* kspart = ws + OFF_KSP;
    float* kv     = ws + OFF_KV;
    float* ksum   = ws + OFF_KS;
    unsigned short* xa   = (unsigned short*)(ws + OFF_XA);
    unsigned short* wb   = (unsigned short*)(ws + OFF_WB);
    unsigned short* kvqb = (unsigned short*)(ws + OFF_KVQB);
    unsigned short* qsb  = (unsigned short*)(ws + OFF_QSB);
    float* out = (float*)d_out;

    // allow 128 KiB dynamic LDS for gemm_qkv (idempotent; not a stream op)
    (void)hipFuncSetAttribute((const void*)gemm_qkv,
                              hipFuncAttributeMaxDynamicSharedMemorySize, 131072);

    dim3 blk(256);
    // cast inputs to bf16
    cast_a<<<(BT*1024/4)/256, blk, 0, stream>>>(x, xa);
    cast_w3<<<(3*1024*1024/4)/256, blk, 0, stream>>>(WQ, WK, WV, wb);
    // combined QKV projection (single-pass bf16 MFMA, K=1024); q -> fp32, k/v -> bf16
    gemm_qkv<<<384, 512, 131072, stream>>>(xa, wb, qf, kfb, vfb);
    // kv & ksum reduction over T (bf16 in, fp32 accum)
    kv_partial<<<dim3(32, NCH), blk, 0, stream>>>(kfb, vfb, kvpart, kspart);
    kv_reduce<<<(32*4096 + 32*64 + 255)/256, blk, 0, stream>>>(kvpart, kspart, kv, ksum);
    // fold output projection into kv -> bf16
    kvpb_kernel<<<(32*1024*64)/256, blk, 0, stream>>>(kv, Wp, kvqb);
    // fused normalizer + z*q -> bf16 (fp32 q path, correlated rounding)
    zq_kernel<<<(BT*Hh)/16, blk, 0, stream>>>(qf, ksum, qsb);
    // final: out = (z*q) @ kvq, K=64
    fgemm<<<dim3(8, 32, 32), blk, 0, stream>>>(qsb, kvqb, out);
}